// Round 1
// baseline (1154.927 us; speedup 1.0000x reference)
//
#include <hip/hip_runtime.h>
#include <math.h>
#include <limits.h>

// Problem constants (from setup_inputs: x[10000,64] f32, k=5)
#define D 64
#define K 5
#define NSPLIT 13   // column splits -> 157*13 = 2041 blocks, saturates 256 CUs

// ---------------------------------------------------------------------------
// Kernel A: row squared norms  xx[i] = sum_d x[i][d]^2
// ---------------------------------------------------------------------------
__global__ void row_norms(const float* __restrict__ x, float* __restrict__ xx, int N) {
    int i = blockIdx.x * 256 + threadIdx.x;
    if (i >= N) return;
    const float4* p = (const float4*)(x + (size_t)i * D);
    float s = 0.f;
#pragma unroll
    for (int t = 0; t < D / 4; ++t) {
        float4 v = p[t];
        s += v.x * v.x + v.y * v.y + v.z * v.z + v.w * v.w;
    }
    xx[i] = s;
}

// ---------------------------------------------------------------------------
// Kernel B: partial top-5 per (row, column-split).
// Block = 256 threads = 4 waves. lane = row-within-tile (64 rows/block),
// wave g handles columns c ≡ g (mod 4) of this split. Row held in 64 VGPRs;
// column vectors are wave-uniform broadcast loads (L2-resident, 2.56 MB total).
// Strict '>' insert + increasing column order per thread == lax.top_k
// tie-break (lowest index wins on equal values).
// ---------------------------------------------------------------------------
__global__ __launch_bounds__(256) void topk_partial(
    const float* __restrict__ x, const float* __restrict__ xx, int N,
    int colsPerSplit, float* __restrict__ wsVal, int* __restrict__ wsIdx)
{
    __shared__ float lv[64][4 * K];
    __shared__ int   li[64][4 * K];

    const int lane = threadIdx.x & 63;
    const int g    = threadIdx.x >> 6;
    const int row0 = blockIdx.x * 64;
    const int r    = row0 + lane;
    const int rr   = (r < N) ? r : 0;   // clamp; invalid rows skipped at write

    float4 a[D / 4];
    const float4* rp = (const float4*)(x + (size_t)rr * D);
#pragma unroll
    for (int t = 0; t < D / 4; ++t) a[t] = rp[t];
    const float nx = xx[rr];

    float tv[K]; int ti[K];
#pragma unroll
    for (int m = 0; m < K; ++m) { tv[m] = -INFINITY; ti[m] = INT_MAX; }

    const int cbeg = blockIdx.y * colsPerSplit;
    const int cend = min(cbeg + colsPerSplit, N);

    for (int c = cbeg + g; c < cend; c += 4) {
        const float4* cp = (const float4*)(x + (size_t)c * D);
        float acc = 0.f;
#pragma unroll
        for (int t = 0; t < D / 4; ++t) {
            float4 b = cp[t];
            acc += a[t].x * b.x;
            acc += a[t].y * b.y;
            acc += a[t].z * b.z;
            acc += a[t].w * b.w;
        }
        float d = 2.f * acc - nx - xx[c];   // pd[i][j] = 2*inner - ||xi||^2 - ||xj||^2
        if (d > tv[4]) {
            if (d > tv[0])      { tv[4]=tv[3];ti[4]=ti[3]; tv[3]=tv[2];ti[3]=ti[2]; tv[2]=tv[1];ti[2]=ti[1]; tv[1]=tv[0];ti[1]=ti[0]; tv[0]=d; ti[0]=c; }
            else if (d > tv[1]) { tv[4]=tv[3];ti[4]=ti[3]; tv[3]=tv[2];ti[3]=ti[2]; tv[2]=tv[1];ti[2]=ti[1]; tv[1]=d; ti[1]=c; }
            else if (d > tv[2]) { tv[4]=tv[3];ti[4]=ti[3]; tv[3]=tv[2];ti[3]=ti[2]; tv[2]=d; ti[2]=c; }
            else if (d > tv[3]) { tv[4]=tv[3];ti[4]=ti[3]; tv[3]=d; ti[3]=c; }
            else                { tv[4]=d; ti[4]=c; }
        }
    }

#pragma unroll
    for (int m = 0; m < K; ++m) { lv[lane][g * K + m] = tv[m]; li[lane][g * K + m] = ti[m]; }
    __syncthreads();

    // Merge the 4 column-groups for each row; one thread per row.
    if (threadIdx.x < 64) {
        int row = row0 + threadIdx.x;
        if (row < N) {
            float bv[K]; int bi[K];
#pragma unroll
            for (int m = 0; m < K; ++m) { bv[m] = -INFINITY; bi[m] = INT_MAX; }
            for (int t = 0; t < 4 * K; ++t) {
                float v = lv[threadIdx.x][t]; int id = li[threadIdx.x][t];
                if ((v > bv[4]) || (v == bv[4] && id < bi[4])) {
                    if ((v > bv[0]) || (v == bv[0] && id < bi[0]))      { bv[4]=bv[3];bi[4]=bi[3]; bv[3]=bv[2];bi[3]=bi[2]; bv[2]=bv[1];bi[2]=bi[1]; bv[1]=bv[0];bi[1]=bi[0]; bv[0]=v; bi[0]=id; }
                    else if ((v > bv[1]) || (v == bv[1] && id < bi[1])) { bv[4]=bv[3];bi[4]=bi[3]; bv[3]=bv[2];bi[3]=bi[2]; bv[2]=bv[1];bi[2]=bi[1]; bv[1]=v; bi[1]=id; }
                    else if ((v > bv[2]) || (v == bv[2] && id < bi[2])) { bv[4]=bv[3];bi[4]=bi[3]; bv[3]=bv[2];bi[3]=bi[2]; bv[2]=v; bi[2]=id; }
                    else if ((v > bv[3]) || (v == bv[3] && id < bi[3])) { bv[4]=bv[3];bi[4]=bi[3]; bv[3]=v; bi[3]=id; }
                    else                                                { bv[4]=v; bi[4]=id; }
                }
            }
            size_t base = ((size_t)row * NSPLIT + blockIdx.y) * K;
#pragma unroll
            for (int m = 0; m < K; ++m) { wsVal[base + m] = bv[m]; wsIdx[base + m] = bi[m]; }
        }
    }
}

// ---------------------------------------------------------------------------
// Kernel C: per row, merge NSPLIT partial top-5 lists -> final top-5, then
// symmetric scatter-add: out[i][j] += v, out[j][i] += v (skip diagonal; it is
// zeroed in the reference). atomicAdd because (i,j) and (j,i) rows race.
// ---------------------------------------------------------------------------
__global__ void merge_scatter(const float* __restrict__ wsVal, const int* __restrict__ wsIdx,
                              float* __restrict__ out, int N)
{
    int i = blockIdx.x * 256 + threadIdx.x;
    if (i >= N) return;
    const float* pv = wsVal + (size_t)i * NSPLIT * K;
    const int*   pi = wsIdx + (size_t)i * NSPLIT * K;

    float bv[K]; int bi[K];
#pragma unroll
    for (int m = 0; m < K; ++m) { bv[m] = -INFINITY; bi[m] = INT_MAX; }
    for (int t = 0; t < NSPLIT * K; ++t) {
        float v = pv[t]; int id = pi[t];
        if ((v > bv[4]) || (v == bv[4] && id < bi[4])) {
            if ((v > bv[0]) || (v == bv[0] && id < bi[0]))      { bv[4]=bv[3];bi[4]=bi[3]; bv[3]=bv[2];bi[3]=bi[2]; bv[2]=bv[1];bi[2]=bi[1]; bv[1]=bv[0];bi[1]=bi[0]; bv[0]=v; bi[0]=id; }
            else if ((v > bv[1]) || (v == bv[1] && id < bi[1])) { bv[4]=bv[3];bi[4]=bi[3]; bv[3]=bv[2];bi[3]=bi[2]; bv[2]=bv[1];bi[2]=bi[1]; bv[1]=v; bi[1]=id; }
            else if ((v > bv[2]) || (v == bv[2] && id < bi[2])) { bv[4]=bv[3];bi[4]=bi[3]; bv[3]=bv[2];bi[3]=bi[2]; bv[2]=v; bi[2]=id; }
            else if ((v > bv[3]) || (v == bv[3] && id < bi[3])) { bv[4]=bv[3];bi[4]=bi[3]; bv[3]=v; bi[3]=id; }
            else                                                { bv[4]=v; bi[4]=id; }
        }
    }

#pragma unroll
    for (int m = 0; m < K; ++m) {
        int j = bi[m]; float v = bv[m];
        if (j != i && (unsigned)j < (unsigned)N) {
            atomicAdd(out + (size_t)i * N + j, v);
            atomicAdd(out + (size_t)j * N + i, v);
        }
    }
}

// ---------------------------------------------------------------------------
extern "C" void kernel_launch(void* const* d_in, const int* in_sizes, int n_in,
                              void* d_out, int out_size, void* d_ws, size_t ws_size,
                              hipStream_t stream) {
    const float* x = (const float*)d_in[0];
    const int N = in_sizes[0] / D;          // 10000
    float* out = (float*)d_out;

    // Workspace layout: xx[N] | wsVal[N*NSPLIT*K] | wsIdx[N*NSPLIT*K]  (~5.3 MB)
    float* xx    = (float*)d_ws;
    float* wsVal = xx + N;
    int*   wsIdx = (int*)(wsVal + (size_t)N * NSPLIT * K);

    // Output is poisoned 0xAA every timed call -> must zero all 400 MB.
    hipMemsetAsync(d_out, 0, (size_t)out_size * sizeof(float), stream);

    row_norms<<<(N + 255) / 256, 256, 0, stream>>>(x, xx, N);

    const int rowBlocks = (N + 63) / 64;                    // 157
    const int colsPerSplit = (N + NSPLIT - 1) / NSPLIT;     // 770
    dim3 grid(rowBlocks, NSPLIT);
    topk_partial<<<grid, 256, 0, stream>>>(x, xx, N, colsPerSplit, wsVal, wsIdx);

    merge_scatter<<<(N + 255) / 256, 256, 0, stream>>>(wsVal, wsIdx, out, N);
}

// Round 2
// 916.833 us; speedup vs baseline: 1.2597x; 1.2597x over previous
//
#include <hip/hip_runtime.h>
#include <math.h>
#include <limits.h>

#define D 64
#define K 5
#define NSPLIT 13
#define TILE 128            // rows per block == cols per tile

// ---------------------------------------------------------------------------
__global__ void row_norms(const float* __restrict__ x, float* __restrict__ xx, int N) {
    int i = blockIdx.x * 256 + threadIdx.x;
    if (i >= N) return;
    const float4* p = (const float4*)(x + (size_t)i * D);
    float s = 0.f;
#pragma unroll
    for (int t = 0; t < D / 4; ++t) {
        float4 v = p[t];
        s += v.x * v.x + v.y * v.y + v.z * v.z + v.w * v.w;
    }
    xx[i] = s;
}

// top-5 insert, strict > (earlier/lower col index wins ties; cols visited ascending)
__device__ __forceinline__ void ins5(float d, int c, float tv[K], int ti[K]) {
    if (d > tv[4]) {
        if (d > tv[0])      { tv[4]=tv[3];ti[4]=ti[3]; tv[3]=tv[2];ti[3]=ti[2]; tv[2]=tv[1];ti[2]=ti[1]; tv[1]=tv[0];ti[1]=ti[0]; tv[0]=d; ti[0]=c; }
        else if (d > tv[1]) { tv[4]=tv[3];ti[4]=ti[3]; tv[3]=tv[2];ti[3]=ti[2]; tv[2]=tv[1];ti[2]=ti[1]; tv[1]=d; ti[1]=c; }
        else if (d > tv[2]) { tv[4]=tv[3];ti[4]=ti[3]; tv[3]=tv[2];ti[3]=ti[2]; tv[2]=d; ti[2]=c; }
        else if (d > tv[3]) { tv[4]=tv[3];ti[4]=ti[3]; tv[3]=d; ti[3]=c; }
        else                { tv[4]=d; ti[4]=c; }
    }
}

// insert with (value, then lower-index) tie-break — for cross-thread merges
__device__ __forceinline__ void ins5tie(float v, int id, float bv[K], int bi[K]) {
    if ((v > bv[4]) || (v == bv[4] && id < bi[4])) {
        if ((v > bv[0]) || (v == bv[0] && id < bi[0]))      { bv[4]=bv[3];bi[4]=bi[3]; bv[3]=bv[2];bi[3]=bi[2]; bv[2]=bv[1];bi[2]=bi[1]; bv[1]=bv[0];bi[1]=bi[0]; bv[0]=v; bi[0]=id; }
        else if ((v > bv[1]) || (v == bv[1] && id < bi[1])) { bv[4]=bv[3];bi[4]=bi[3]; bv[3]=bv[2];bi[3]=bi[2]; bv[2]=bv[1];bi[2]=bi[1]; bv[1]=v; bi[1]=id; }
        else if ((v > bv[2]) || (v == bv[2] && id < bi[2])) { bv[4]=bv[3];bi[4]=bi[3]; bv[3]=bv[2];bi[3]=bi[2]; bv[2]=v; bi[2]=id; }
        else if ((v > bv[3]) || (v == bv[3] && id < bi[3])) { bv[4]=bv[3];bi[4]=bi[3]; bv[3]=v; bi[3]=id; }
        else                                                { bv[4]=v; bi[4]=id; }
    }
}

// ---------------------------------------------------------------------------
// Block: 256 threads (16x16), computes a 128-row stripe x a strided set of
// 128-col tiles. Per-thread 8x8 fragment; A/B staged transposed in LDS so
// fragment reads are ds_read_b128. Also zeroes a slice of `out`, striped
// across tile iterations so the stores drain under the k-loop.
// ---------------------------------------------------------------------------
__global__ __launch_bounds__(256, 2) void topk_tiled(
    const float* __restrict__ x, const float* __restrict__ xx, int N,
    float* __restrict__ wsVal, int* __restrict__ wsIdx,
    float4* __restrict__ outZ, long long totalF4, int f4PerBlock)
{
    __shared__ union SH {
        struct { float A[D * TILE]; float B[D * TILE]; } ab;   // [k][row], [k][col]
        struct { float mv[64][16 * K]; int mi[64][16 * K]; } mg;
    } sh;

    const int tid  = threadIdx.x;
    const int tx   = tid & 15;           // col group (8 cols)
    const int ty   = tid >> 4;           // row group (8 rows)
    const int row0 = blockIdx.x * TILE;
    const int split = blockIdx.y;
    const int nTilesTotal = (N + TILE - 1) / TILE;   // 79

    // ---- zero-fill bookkeeping (this block's slice of out) ----
    const int bid = blockIdx.y * gridDim.x + blockIdx.x;
    long long zbeg = (long long)bid * f4PerBlock;
    long long zend = zbeg + f4PerBlock; if (zend > totalF4) zend = totalF4;
    int nIters = 0;
    for (int t = split; t < nTilesTotal; t += NSPLIT) ++nIters;
    const long long zChunk = (f4PerBlock + nIters - 1) / nIters;
    const float4 zero4 = {0.f, 0.f, 0.f, 0.f};

    // ---- stage A (rows row0..row0+127), transposed into [k][row] ----
    {
        int srow = tid >> 1, kh = (tid & 1) * 32;
        int gr = row0 + srow; if (gr >= N) gr = 0;
        const float4* src = (const float4*)(x + (size_t)gr * D + kh);
#pragma unroll
        for (int j = 0; j < 8; ++j) {
            float4 v = src[j];
            int k = kh + 4 * j;
            sh.ab.A[(k + 0) * TILE + srow] = v.x;
            sh.ab.A[(k + 1) * TILE + srow] = v.y;
            sh.ab.A[(k + 2) * TILE + srow] = v.z;
            sh.ab.A[(k + 3) * TILE + srow] = v.w;
        }
    }

    // row norms for my 8 rows
    float nx[8];
#pragma unroll
    for (int r = 0; r < 8; ++r) {
        int gr = row0 + 8 * ty + r;
        nx[r] = xx[(gr < N) ? gr : 0];
    }

    float tv[8][K]; int ti[8][K];
#pragma unroll
    for (int r = 0; r < 8; ++r)
#pragma unroll
        for (int m = 0; m < K; ++m) { tv[r][m] = -INFINITY; ti[r][m] = INT_MAX; }

    // ---- main loop over this split's column tiles ----
    int it = 0;
    for (int t = split; t < nTilesTotal; t += NSPLIT, ++it) {
        const int c0 = t * TILE;

        __syncthreads();   // previous compute finished before overwriting B

        // zero-fill stripe for this iteration (stores drain under the k-loop)
        {
            long long s = zbeg + (long long)it * zChunk;
            long long e = s + zChunk; if (e > zend) e = zend;
            for (long long i = s + tid; i < e; i += 256) outZ[i] = zero4;
        }

        // stage B (cols c0..c0+127), transposed into [k][col]
        {
            int scol = tid >> 1, kh = (tid & 1) * 32;
            int gc = c0 + scol; if (gc >= N) gc = 0;
            const float4* src = (const float4*)(x + (size_t)gc * D + kh);
#pragma unroll
            for (int j = 0; j < 8; ++j) {
                float4 v = src[j];
                int k = kh + 4 * j;
                sh.ab.B[(k + 0) * TILE + scol] = v.x;
                sh.ab.B[(k + 1) * TILE + scol] = v.y;
                sh.ab.B[(k + 2) * TILE + scol] = v.z;
                sh.ab.B[(k + 3) * TILE + scol] = v.w;
            }
        }
        __syncthreads();

        float xc[8];
#pragma unroll
        for (int i = 0; i < 8; ++i) {
            int gc = c0 + 8 * tx + i;
            xc[i] = xx[(gc < N) ? gc : 0];
        }

        float acc[8][8];
#pragma unroll
        for (int r = 0; r < 8; ++r)
#pragma unroll
            for (int c = 0; c < 8; ++c) acc[r][c] = 0.f;

#pragma unroll 4
        for (int k = 0; k < D; ++k) {
            const float4 a0 = *(const float4*)&sh.ab.A[k * TILE + 8 * ty];
            const float4 a1 = *(const float4*)&sh.ab.A[k * TILE + 8 * ty + 4];
            const float4 b0 = *(const float4*)&sh.ab.B[k * TILE + 8 * tx];
            const float4 b1 = *(const float4*)&sh.ab.B[k * TILE + 8 * tx + 4];
            const float av[8] = {a0.x, a0.y, a0.z, a0.w, a1.x, a1.y, a1.z, a1.w};
            const float bv[8] = {b0.x, b0.y, b0.z, b0.w, b1.x, b1.y, b1.z, b1.w};
#pragma unroll
            for (int r = 0; r < 8; ++r)
#pragma unroll
                for (int c = 0; c < 8; ++c)
                    acc[r][c] = fmaf(av[r], bv[c], acc[r][c]);
        }

        // distances + top-5 insert (cols ascending per row for tie-break)
#pragma unroll
        for (int i = 0; i < 8; ++i) {
            const int c = c0 + 8 * tx + i;
            const bool ok = (c < N);
#pragma unroll
            for (int r = 0; r < 8; ++r) {
                float dval = 2.f * acc[r][i] - nx[r] - xc[i];
                if (ok) ins5(dval, c, tv[r], ti[r]);
            }
        }
    }

    // ---- merge the 16 tx-lists per row, in two 64-row phases ----
    for (int p = 0; p < 2; ++p) {
        __syncthreads();
#pragma unroll
        for (int r = 0; r < 8; ++r) {
            int row_loc = 8 * ty + r;
            if ((row_loc >> 6) == p) {
#pragma unroll
                for (int m = 0; m < K; ++m) {
                    sh.mg.mv[row_loc & 63][tx * K + m] = tv[r][m];
                    sh.mg.mi[row_loc & 63][tx * K + m] = ti[r][m];
                }
            }
        }
        __syncthreads();
        if (tid < 64) {
            int gr = row0 + p * 64 + tid;
            if (gr < N) {
                float bv[K]; int bi[K];
#pragma unroll
                for (int m = 0; m < K; ++m) { bv[m] = -INFINITY; bi[m] = INT_MAX; }
                for (int q = 0; q < 16 * K; ++q)
                    ins5tie(sh.mg.mv[tid][q], sh.mg.mi[tid][q], bv, bi);
                size_t base = ((size_t)gr * NSPLIT + split) * K;
#pragma unroll
                for (int m = 0; m < K; ++m) { wsVal[base + m] = bv[m]; wsIdx[base + m] = bi[m]; }
            }
        }
    }
}

// ---------------------------------------------------------------------------
__global__ void merge_scatter(const float* __restrict__ wsVal, const int* __restrict__ wsIdx,
                              float* __restrict__ out, int N)
{
    int i = blockIdx.x * 256 + threadIdx.x;
    if (i >= N) return;
    const float* pv = wsVal + (size_t)i * NSPLIT * K;
    const int*   pi = wsIdx + (size_t)i * NSPLIT * K;

    float bv[K]; int bi[K];
#pragma unroll
    for (int m = 0; m < K; ++m) { bv[m] = -INFINITY; bi[m] = INT_MAX; }
    for (int t = 0; t < NSPLIT * K; ++t) ins5tie(pv[t], pi[t], bv, bi);

#pragma unroll
    for (int m = 0; m < K; ++m) {
        int j = bi[m]; float v = bv[m];
        if (j != i && (unsigned)j < (unsigned)N) {
            atomicAdd(out + (size_t)i * N + j, v);
            atomicAdd(out + (size_t)j * N + i, v);
        }
    }
}

// ---------------------------------------------------------------------------
extern "C" void kernel_launch(void* const* d_in, const int* in_sizes, int n_in,
                              void* d_out, int out_size, void* d_ws, size_t ws_size,
                              hipStream_t stream) {
    const float* x = (const float*)d_in[0];
    const int N = in_sizes[0] / D;          // 10000
    float* out = (float*)d_out;

    // Workspace: xx[N] | wsVal[N*NSPLIT*K] | wsIdx[N*NSPLIT*K]  (~5.3 MB)
    float* xx    = (float*)d_ws;
    float* wsVal = xx + N;
    int*   wsIdx = (int*)(wsVal + (size_t)N * NSPLIT * K);

    row_norms<<<(N + 255) / 256, 256, 0, stream>>>(x, xx, N);

    const int rowBlocks = (N + TILE - 1) / TILE;     // 79
    dim3 grid(rowBlocks, NSPLIT);                    // 1027 blocks
    long long totalF4 = (long long)out_size / 4;     // 25e6 float4s
    int nBlocks = rowBlocks * NSPLIT;
    int f4PerBlock = (int)((totalF4 + nBlocks - 1) / nBlocks);
    topk_tiled<<<grid, 256, 0, stream>>>(x, xx, N, wsVal, wsIdx,
                                         (float4*)out, totalF4, f4PerBlock);

    merge_scatter<<<(N + 255) / 256, 256, 0, stream>>>(wsVal, wsIdx, out, N);
}

// Round 3
// 783.782 us; speedup vs baseline: 1.4735x; 1.1698x over previous
//
#include <hip/hip_runtime.h>
#include <math.h>
#include <limits.h>

#define D 64
#define K 5
#define XTP 10112            // padded leading dim of xT (>= 79*128, mult of 64)
typedef unsigned long long u64;

// ---------------------------------------------------------------------------
// top-5 insert, strict > (cols visited ascending -> lower index wins ties)
__device__ __forceinline__ void ins5(float d, int c, float tv[K], int ti[K]) {
    if (d > tv[4]) {
        if (d > tv[0])      { tv[4]=tv[3];ti[4]=ti[3]; tv[3]=tv[2];ti[3]=ti[2]; tv[2]=tv[1];ti[2]=ti[1]; tv[1]=tv[0];ti[1]=ti[0]; tv[0]=d; ti[0]=c; }
        else if (d > tv[1]) { tv[4]=tv[3];ti[4]=ti[3]; tv[3]=tv[2];ti[3]=ti[2]; tv[2]=tv[1];ti[2]=ti[1]; tv[1]=d; ti[1]=c; }
        else if (d > tv[2]) { tv[4]=tv[3];ti[4]=ti[3]; tv[3]=tv[2];ti[3]=ti[2]; tv[2]=d; ti[2]=c; }
        else if (d > tv[3]) { tv[4]=tv[3];ti[4]=ti[3]; tv[3]=d; ti[3]=c; }
        else                { tv[4]=d; ti[4]=c; }
    }
}

// value-then-lower-index tie-break (float domain) — for final cross-split merge
__device__ __forceinline__ void ins5tie(float v, int id, float bv[K], int bi[K]) {
    if ((v > bv[4]) || (v == bv[4] && id < bi[4])) {
        if ((v > bv[0]) || (v == bv[0] && id < bi[0]))      { bv[4]=bv[3];bi[4]=bi[3]; bv[3]=bv[2];bi[3]=bi[2]; bv[2]=bv[1];bi[2]=bi[1]; bv[1]=bv[0];bi[1]=bi[0]; bv[0]=v; bi[0]=id; }
        else if ((v > bv[1]) || (v == bv[1] && id < bi[1])) { bv[4]=bv[3];bi[4]=bi[3]; bv[3]=bv[2];bi[3]=bi[2]; bv[2]=bv[1];bi[2]=bi[1]; bv[1]=v; bi[1]=id; }
        else if ((v > bv[2]) || (v == bv[2] && id < bi[2])) { bv[4]=bv[3];bi[4]=bi[3]; bv[3]=bv[2];bi[3]=bi[2]; bv[2]=v; bi[2]=id; }
        else if ((v > bv[3]) || (v == bv[3] && id < bi[3])) { bv[4]=bv[3];bi[4]=bi[3]; bv[3]=v; bi[3]=id; }
        else                                                { bv[4]=v; bi[4]=id; }
    }
}

// pack (value, idx) into sortable u64: bigger == (bigger value, then lower idx)
__device__ __forceinline__ u64 packKV(float v, int idx) {
    unsigned u = __float_as_uint(v);
    u = (u & 0x80000000u) ? ~u : (u | 0x80000000u);
    return ((u64)u << 32) | (unsigned)(~idx);
}

// merge two descending sorted 5-lists (in registers, branchless) -> a = top5
__device__ __forceinline__ void merge5(u64 a[K], const u64 b[K]) {
    u64 a0=a[0],a1=a[1],a2=a[2],a3=a[3],a4=a[4];
    u64 b0=b[0],b1=b[1],b2=b[2],b3=b[3],b4=b[4];
    u64 c[K];
#pragma unroll
    for (int m = 0; m < K; ++m) {
        bool ta = a0 >= b0;
        c[m] = ta ? a0 : b0;
        u64 na0 = ta ? a1 : a0, na1 = ta ? a2 : a1, na2 = ta ? a3 : a2, na3 = ta ? a4 : a3;
        u64 nb0 = ta ? b0 : b1, nb1 = ta ? b1 : b2, nb2 = ta ? b2 : b3, nb3 = ta ? b3 : b4;
        a0=na0; a1=na1; a2=na2; a3=na3;
        b0=nb0; b1=nb1; b2=nb2; b3=nb3;
    }
#pragma unroll
    for (int m = 0; m < K; ++m) a[m] = c[m];
}

// ---------------------------------------------------------------------------
// Transpose x[N][64] -> xT[64][XTP] (pad cols zero) + row squared norms.
// ---------------------------------------------------------------------------
__global__ __launch_bounds__(256) void transpose_norms(
    const float* __restrict__ x, float* __restrict__ xT, float* __restrict__ xx, int N)
{
    __shared__ float tile[D][65];
    const int tid = threadIdx.x;
    const int n0 = blockIdx.x * 64;
    const int row = tid >> 2;      // 0..63
    const int chunk = tid & 3;     // 0..3
    const int gr = n0 + row;
    const float4 z4 = {0.f, 0.f, 0.f, 0.f};
#pragma unroll
    for (int p = 0; p < 4; ++p) {
        int fc = chunk + 4 * p;    // float4 index within the row, 0..15
        float4 v = (gr < N) ? ((const float4*)x)[(size_t)gr * 16 + fc] : z4;
        int kb = fc * 4;
        tile[kb+0][row] = v.x; tile[kb+1][row] = v.y;
        tile[kb+2][row] = v.z; tile[kb+3][row] = v.w;
    }
    __syncthreads();
#pragma unroll
    for (int p = 0; p < 4; ++p) {
        int k  = p * 16 + (tid >> 4);
        int cg = tid & 15;
        float4 v = { tile[k][cg*4+0], tile[k][cg*4+1], tile[k][cg*4+2], tile[k][cg*4+3] };
        ((float4*)xT)[(size_t)k * (XTP/4) + (n0 >> 2) + cg] = v;
    }
    if (tid < 64) {
        float s = 0.f;
#pragma unroll
        for (int k = 0; k < D; ++k) { float t = tile[k][tid]; s = fmaf(t, t, s); }
        int g = n0 + tid;
        if (g < N) xx[g] = s;
    }
}

// ---------------------------------------------------------------------------
// Main kernel: NO LDS, NO barriers. Block = 256 threads (16 tx x 16 ty),
// tile = 64 rows x 128 cols, per-thread fragment 4 rows x 8 cols.
// A/B fragments read straight from xT (L1/L2-resident, coalesced dwordx4).
// Cross-thread top-5 merge: shfl_xor butterfly over the 16 tx lanes.
// Also zeroes a slice of `out`, striped across tile iterations.
// ---------------------------------------------------------------------------
__global__ __launch_bounds__(256, 4) void topk_nolds(
    const float* __restrict__ xT, const float* __restrict__ xx, int N, int nsplit,
    float* __restrict__ wsVal, int* __restrict__ wsIdx,
    float4* __restrict__ outZ, long long totalF4, int f4PerBlock)
{
    const int tid = threadIdx.x;
    const int tx = tid & 15, ty = tid >> 4;
    const int row0 = blockIdx.x * 64;
    const int split = blockIdx.y;
    const int nTiles = (N + 127) / 128;   // 79

    // zero-fill bookkeeping
    const int bid = split * gridDim.x + blockIdx.x;
    long long zbeg = (long long)bid * f4PerBlock;
    long long zend = zbeg + f4PerBlock; if (zend > totalF4) zend = totalF4;
    const int nIters = (nTiles - split + nsplit - 1) / nsplit;
    const long long zChunk = (f4PerBlock + nIters - 1) / nIters;
    const float4 zero4 = {0.f, 0.f, 0.f, 0.f};

    const int rbase = row0 + 4 * ty;       // my 4 rows: rbase..rbase+3
    float nx[4];
#pragma unroll
    for (int r = 0; r < 4; ++r) { int g = rbase + r; nx[r] = xx[(g < N) ? g : 0]; }

    float tv[4][K]; int ti[4][K];
#pragma unroll
    for (int r = 0; r < 4; ++r)
#pragma unroll
        for (int m = 0; m < K; ++m) { tv[r][m] = -INFINITY; ti[r][m] = INT_MAX; }

    const float* aBase = xT + rbase;

    int it = 0;
    for (int t = split; t < nTiles; t += nsplit, ++it) {
        const int c0 = t * 128;

        // zero stripe for this iteration (stores drain under the k-loop)
        {
            long long s = zbeg + (long long)it * zChunk;
            long long e = s + zChunk; if (e > zend) e = zend;
            for (long long i = s + tid; i < e; i += 256) outZ[i] = zero4;
        }

        const float* bBase = xT + (c0 + 8 * tx);

        float acc[4][8];
#pragma unroll
        for (int r = 0; r < 4; ++r)
#pragma unroll
            for (int c = 0; c < 8; ++c) acc[r][c] = 0.f;

#pragma unroll 4
        for (int k = 0; k < D; ++k) {
            const float4 a0 = *(const float4*)(aBase + (size_t)k * XTP);
            const float4 b0 = *(const float4*)(bBase + (size_t)k * XTP);
            const float4 b1 = *(const float4*)(bBase + (size_t)k * XTP + 4);
            const float av[4] = {a0.x, a0.y, a0.z, a0.w};
            const float bv[8] = {b0.x, b0.y, b0.z, b0.w, b1.x, b1.y, b1.z, b1.w};
#pragma unroll
            for (int r = 0; r < 4; ++r)
#pragma unroll
                for (int c = 0; c < 8; ++c)
                    acc[r][c] = fmaf(av[r], bv[c], acc[r][c]);
        }

        // candidates: keys in (acc - 0.5*xc) domain; final val = 2*key - nx
        float hxc[8];
#pragma unroll
        for (int i = 0; i < 8; ++i) {
            int g = c0 + 8 * tx + i;
            hxc[i] = 0.5f * xx[(g < N) ? g : 0];
        }
#pragma unroll
        for (int i = 0; i < 8; ++i) {
            const int c = c0 + 8 * tx + i;
            const bool ok = (c < N);
#pragma unroll
            for (int r = 0; r < 4; ++r) {
                float dk = acc[r][i] - hxc[i];
                if (ok) ins5(dk, c, tv[r], ti[r]);
            }
        }
    }

    // butterfly merge across the 16 tx lanes (all hold lists for the same rows)
#pragma unroll
    for (int r = 0; r < 4; ++r) {
        u64 L[K];
#pragma unroll
        for (int m = 0; m < K; ++m) L[m] = packKV(tv[r][m], ti[r][m]);
#pragma unroll
        for (int mask = 1; mask <= 8; mask <<= 1) {
            u64 P[K];
#pragma unroll
            for (int m = 0; m < K; ++m) P[m] = __shfl_xor(L[m], mask, 16);
            merge5(L, P);
        }
        if (tx == 0) {
            int g = rbase + r;
            if (g < N) {
                size_t base = ((size_t)g * nsplit + split) * K;
#pragma unroll
                for (int m = 0; m < K; ++m) {
                    unsigned hu = (unsigned)(L[m] >> 32);
                    float dk = (hu & 0x80000000u) ? __uint_as_float(hu & 0x7fffffffu)
                                                  : __uint_as_float(~hu);
                    int idx = (int)(~(unsigned)L[m]);
                    wsVal[base + m] = 2.f * dk - nx[r];
                    wsIdx[base + m] = idx;
                }
            }
        }
    }
}

// ---------------------------------------------------------------------------
// Merge nsplit partial lists per row -> final top-5, symmetric scatter-add.
// ---------------------------------------------------------------------------
__global__ void merge_scatter(const float* __restrict__ wsVal, const int* __restrict__ wsIdx,
                              float* __restrict__ out, int N, int nsplit)
{
    int i = blockIdx.x * 256 + threadIdx.x;
    if (i >= N) return;
    const float* pv = wsVal + (size_t)i * nsplit * K;
    const int*   pi = wsIdx + (size_t)i * nsplit * K;

    float bv[K]; int bi[K];
#pragma unroll
    for (int m = 0; m < K; ++m) { bv[m] = -INFINITY; bi[m] = INT_MAX; }
    for (int t = 0; t < nsplit * K; ++t) ins5tie(pv[t], pi[t], bv, bi);

#pragma unroll
    for (int m = 0; m < K; ++m) {
        int j = bi[m]; float v = bv[m];
        if (j != i && (unsigned)j < (unsigned)N) {
            atomicAdd(out + (size_t)i * N + j, v);
            atomicAdd(out + (size_t)j * N + i, v);
        }
    }
}

// ---------------------------------------------------------------------------
extern "C" void kernel_launch(void* const* d_in, const int* in_sizes, int n_in,
                              void* d_out, int out_size, void* d_ws, size_t ws_size,
                              hipStream_t stream) {
    const float* x = (const float*)d_in[0];
    const int N = in_sizes[0] / D;          // 10000
    float* out = (float*)d_out;

    // Workspace layout (floats): xT[64*XTP] | xx[10048 pad] | wsVal | wsIdx
    const size_t oXT = 0;
    const size_t oXX = (size_t)D * XTP;                 // 647168
    const size_t oV  = oXX + 10048;
    // pick largest nsplit whose ws fits
    int nsplit = 13;
    while (nsplit > 1) {
        size_t need = (oV + 2 * (size_t)N * nsplit * K) * sizeof(float);
        if (need <= ws_size) break;
        nsplit = (nsplit == 13) ? 8 : (nsplit == 8) ? 4 : (nsplit == 4) ? 2 : 1;
    }
    float* xT    = (float*)d_ws + oXT;
    float* xx    = (float*)d_ws + oXX;
    float* wsVal = (float*)d_ws + oV;
    int*   wsIdx = (int*)(wsVal + (size_t)N * nsplit * K);

    transpose_norms<<<XTP / 64, 256, 0, stream>>>(x, xT, xx, N);   // 158 blocks

    const int rowBlocks = (N + 63) / 64;                 // 157
    dim3 grid(rowBlocks, nsplit);
    long long totalF4 = (long long)out_size / 4;         // 25e6
    int nBlocks = rowBlocks * nsplit;
    int f4PerBlock = (int)((totalF4 + nBlocks - 1) / nBlocks);
    topk_nolds<<<grid, 256, 0, stream>>>(xT, xx, N, nsplit, wsVal, wsIdx,
                                         (float4*)out, totalF4, f4PerBlock);

    merge_scatter<<<(N + 255) / 256, 256, 0, stream>>>(wsVal, wsIdx, out, N, nsplit);
}

// Round 4
// 749.344 us; speedup vs baseline: 1.5413x; 1.0460x over previous
//
#include <hip/hip_runtime.h>
#include <math.h>
#include <limits.h>

#define D 64
#define K 5
#define XTP 10112            // padded leading dim of xT (= 79*128, mult of 64)
typedef unsigned long long u64;
typedef float f32x2 __attribute__((ext_vector_type(2)));
typedef float f32x4 __attribute__((ext_vector_type(4)));

// ---------------------------------------------------------------------------
// top-5 insert, strict > (cols visited ascending -> lower index wins ties)
__device__ __forceinline__ void ins5(float d, int c, float tv[K], int ti[K]) {
    if (d > tv[4]) {
        if (d > tv[0])      { tv[4]=tv[3];ti[4]=ti[3]; tv[3]=tv[2];ti[3]=ti[2]; tv[2]=tv[1];ti[2]=ti[1]; tv[1]=tv[0];ti[1]=ti[0]; tv[0]=d; ti[0]=c; }
        else if (d > tv[1]) { tv[4]=tv[3];ti[4]=ti[3]; tv[3]=tv[2];ti[3]=ti[2]; tv[2]=tv[1];ti[2]=ti[1]; tv[1]=d; ti[1]=c; }
        else if (d > tv[2]) { tv[4]=tv[3];ti[4]=ti[3]; tv[3]=tv[2];ti[3]=ti[2]; tv[2]=d; ti[2]=c; }
        else if (d > tv[3]) { tv[4]=tv[3];ti[4]=ti[3]; tv[3]=d; ti[3]=c; }
        else                { tv[4]=d; ti[4]=c; }
    }
}

// value-then-lower-index tie-break (float domain) — for final cross-split merge
__device__ __forceinline__ void ins5tie(float v, int id, float bv[K], int bi[K]) {
    if ((v > bv[4]) || (v == bv[4] && id < bi[4])) {
        if ((v > bv[0]) || (v == bv[0] && id < bi[0]))      { bv[4]=bv[3];bi[4]=bi[3]; bv[3]=bv[2];bi[3]=bi[2]; bv[2]=bv[1];bi[2]=bi[1]; bv[1]=bv[0];bi[1]=bi[0]; bv[0]=v; bi[0]=id; }
        else if ((v > bv[1]) || (v == bv[1] && id < bi[1])) { bv[4]=bv[3];bi[4]=bi[3]; bv[3]=bv[2];bi[3]=bi[2]; bv[2]=bv[1];bi[2]=bi[1]; bv[1]=v; bi[1]=id; }
        else if ((v > bv[2]) || (v == bv[2] && id < bi[2])) { bv[4]=bv[3];bi[4]=bi[3]; bv[3]=bv[2];bi[3]=bi[2]; bv[2]=v; bi[2]=id; }
        else if ((v > bv[3]) || (v == bv[3] && id < bi[3])) { bv[4]=bv[3];bi[4]=bi[3]; bv[3]=v; bi[3]=id; }
        else                                                { bv[4]=v; bi[4]=id; }
    }
}

// pack (value, idx) into sortable u64: bigger == (bigger value, then lower idx)
__device__ __forceinline__ u64 packKV(float v, int idx) {
    unsigned u = __float_as_uint(v);
    u = (u & 0x80000000u) ? ~u : (u | 0x80000000u);
    return ((u64)u << 32) | (unsigned)(~idx);
}

// merge two descending sorted 5-lists (registers, branchless) -> a = top5
__device__ __forceinline__ void merge5(u64 a[K], const u64 b[K]) {
    u64 a0=a[0],a1=a[1],a2=a[2],a3=a[3],a4=a[4];
    u64 b0=b[0],b1=b[1],b2=b[2],b3=b[3],b4=b[4];
    u64 c[K];
#pragma unroll
    for (int m = 0; m < K; ++m) {
        bool ta = a0 >= b0;
        c[m] = ta ? a0 : b0;
        u64 na0 = ta ? a1 : a0, na1 = ta ? a2 : a1, na2 = ta ? a3 : a2, na3 = ta ? a4 : a3;
        u64 nb0 = ta ? b0 : b1, nb1 = ta ? b1 : b2, nb2 = ta ? b2 : b3, nb3 = ta ? b3 : b4;
        a0=na0; a1=na1; a2=na2; a3=na3;
        b0=nb0; b1=nb1; b2=nb2; b3=nb3;
    }
#pragma unroll
    for (int m = 0; m < K; ++m) a[m] = c[m];
}

// ---------------------------------------------------------------------------
// Transpose x[N][64] -> xT[64][XTP] (pad cols zero) + HALF row squared norms.
// ---------------------------------------------------------------------------
__global__ __launch_bounds__(256) void transpose_norms(
    const float* __restrict__ x, float* __restrict__ xT, float* __restrict__ hxx, int N)
{
    __shared__ float tile[D][65];
    const int tid = threadIdx.x;
    const int n0 = blockIdx.x * 64;
    const int row = tid >> 2;      // 0..63
    const int chunk = tid & 3;     // 0..3
    const int gr = n0 + row;
    const float4 z4 = {0.f, 0.f, 0.f, 0.f};
#pragma unroll
    for (int p = 0; p < 4; ++p) {
        int fc = chunk + 4 * p;    // float4 index within the row, 0..15
        float4 v = (gr < N) ? ((const float4*)x)[(size_t)gr * 16 + fc] : z4;
        int kb = fc * 4;
        tile[kb+0][row] = v.x; tile[kb+1][row] = v.y;
        tile[kb+2][row] = v.z; tile[kb+3][row] = v.w;
    }
    __syncthreads();
#pragma unroll
    for (int p = 0; p < 4; ++p) {
        int k  = p * 16 + (tid >> 4);
        int cg = tid & 15;
        float4 v = { tile[k][cg*4+0], tile[k][cg*4+1], tile[k][cg*4+2], tile[k][cg*4+3] };
        ((float4*)xT)[(size_t)k * (XTP/4) + (n0 >> 2) + cg] = v;
    }
    if (tid < 64) {
        float s = 0.f;
#pragma unroll
        for (int k = 0; k < D; ++k) { float t = tile[k][tid]; s = fmaf(t, t, s); }
        int g = n0 + tid;
        if (g < N) hxx[g] = 0.5f * s;
    }
}

// ---------------------------------------------------------------------------
// Main kernel: NO LDS/barriers. Block = 256 (16 tx x 16 ty), tile 64x128,
// fragment 4 rows x 8 cols. float2 math -> v_pk_fma_f32 if gfx950 has the
// packed-fp32 pipe. Zero-fill of `out` uses NON-TEMPORAL stores so the
// 403 MB stream does not evict xT from L2/L3 (round-3 FETCH=94MB fix).
// ---------------------------------------------------------------------------
__global__ __launch_bounds__(256, 4) void topk_nolds(
    const float* __restrict__ xT, const float* __restrict__ hxx, int N, int nsplit,
    float* __restrict__ wsVal, int* __restrict__ wsIdx,
    float* __restrict__ outZ, long long totalF4, int f4PerBlock)
{
    const int tid = threadIdx.x;
    const int tx = tid & 15, ty = tid >> 4;
    const int row0 = blockIdx.x * 64;
    const int split = blockIdx.y;
    const int nTiles = (N + 127) / 128;   // 79

    // zero-fill bookkeeping
    const int bid = split * gridDim.x + blockIdx.x;
    long long zbeg = (long long)bid * f4PerBlock;
    long long zend = zbeg + f4PerBlock; if (zend > totalF4) zend = totalF4;
    const int nIters = (nTiles - split + nsplit - 1) / nsplit;
    const long long zChunk = (f4PerBlock + nIters - 1) / nIters;

    const int rbase = row0 + 4 * ty;       // my 4 rows
    float hnx[4];
#pragma unroll
    for (int r = 0; r < 4; ++r) { int g = rbase + r; hnx[r] = hxx[(g < N) ? g : 0]; }

    float tv[4][K]; int ti[4][K];
#pragma unroll
    for (int r = 0; r < 4; ++r)
#pragma unroll
        for (int m = 0; m < K; ++m) { tv[r][m] = -INFINITY; ti[r][m] = INT_MAX; }

    const float* aBase = xT + rbase;

    int it = 0;
    for (int t = split; t < nTiles; t += nsplit, ++it) {
        const int c0 = t * 128;

        // zero stripe (non-temporal: bypass L2/L3, drains under the k-loop)
        {
            long long s = zbeg + (long long)it * zChunk;
            long long e = s + zChunk; if (e > zend) e = zend;
            const f32x4 z = {0.f, 0.f, 0.f, 0.f};
            for (long long i = s + tid; i < e; i += 256)
                __builtin_nontemporal_store(z, (f32x4*)(outZ + 4 * i));
        }

        const float* bBase = xT + (c0 + 8 * tx);

        f32x2 acc2[4][4];
#pragma unroll
        for (int r = 0; r < 4; ++r)
#pragma unroll
            for (int c = 0; c < 4; ++c) acc2[r][c] = (f32x2){0.f, 0.f};

#pragma unroll 8
        for (int k = 0; k < D; ++k) {
            const float4 a0 = *(const float4*)(aBase + (size_t)k * XTP);
            const float4 b0 = *(const float4*)(bBase + (size_t)k * XTP);
            const float4 b1 = *(const float4*)(bBase + (size_t)k * XTP + 4);
            const float av[4] = {a0.x, a0.y, a0.z, a0.w};
            const f32x2 b2[4] = { {b0.x, b0.y}, {b0.z, b0.w}, {b1.x, b1.y}, {b1.z, b1.w} };
#pragma unroll
            for (int r = 0; r < 4; ++r) {
                const f32x2 a2 = {av[r], av[r]};
#pragma unroll
                for (int c = 0; c < 4; ++c)
                    acc2[r][c] = a2 * b2[c] + acc2[r][c];   // -> v_pk_fma_f32
            }
        }

        // candidates: key = inner - 0.5*||xc||^2 ; final val = 2*key - ||xr||^2
        float hxc[8];
#pragma unroll
        for (int i = 0; i < 8; ++i) {
            int g = c0 + 8 * tx + i;
            hxc[i] = hxx[(g < N) ? g : 0];
        }
#pragma unroll
        for (int i = 0; i < 8; ++i) {            // ascending col order
            const int c = c0 + 8 * tx + i;
            const bool ok = (c < N);
#pragma unroll
            for (int r = 0; r < 4; ++r) {
                float ip = (i & 1) ? acc2[r][i >> 1].y : acc2[r][i >> 1].x;
                float dk = ip - hxc[i];
                if (ok) ins5(dk, c, tv[r], ti[r]);
            }
        }
    }

    // butterfly merge across the 16 tx lanes
#pragma unroll
    for (int r = 0; r < 4; ++r) {
        u64 L[K];
#pragma unroll
        for (int m = 0; m < K; ++m) L[m] = packKV(tv[r][m], ti[r][m]);
#pragma unroll
        for (int mask = 1; mask <= 8; mask <<= 1) {
            u64 P[K];
#pragma unroll
            for (int m = 0; m < K; ++m) P[m] = __shfl_xor(L[m], mask, 16);
            merge5(L, P);
        }
        if (tx == 0) {
            int g = rbase + r;
            if (g < N) {
                size_t base = ((size_t)g * nsplit + split) * K;
#pragma unroll
                for (int m = 0; m < K; ++m) {
                    unsigned hu = (unsigned)(L[m] >> 32);
                    float dk = (hu & 0x80000000u) ? __uint_as_float(hu & 0x7fffffffu)
                                                  : __uint_as_float(~hu);
                    int idx = (int)(~(unsigned)L[m]);
                    wsVal[base + m] = 2.f * (dk - hnx[r]);
                    wsIdx[base + m] = idx;
                }
            }
        }
    }
}

// ---------------------------------------------------------------------------
__global__ void merge_scatter(const float* __restrict__ wsVal, const int* __restrict__ wsIdx,
                              float* __restrict__ out, int N, int nsplit)
{
    int i = blockIdx.x * 256 + threadIdx.x;
    if (i >= N) return;
    const float* pv = wsVal + (size_t)i * nsplit * K;
    const int*   pi = wsIdx + (size_t)i * nsplit * K;

    float bv[K]; int bi[K];
#pragma unroll
    for (int m = 0; m < K; ++m) { bv[m] = -INFINITY; bi[m] = INT_MAX; }
    for (int t = 0; t < nsplit * K; ++t) ins5tie(pv[t], pi[t], bv, bi);

#pragma unroll
    for (int m = 0; m < K; ++m) {
        int j = bi[m]; float v = bv[m];
        if (j != i && (unsigned)j < (unsigned)N) {
            atomicAdd(out + (size_t)i * N + j, v);
            atomicAdd(out + (size_t)j * N + i, v);
        }
    }
}

// ---------------------------------------------------------------------------
extern "C" void kernel_launch(void* const* d_in, const int* in_sizes, int n_in,
                              void* d_out, int out_size, void* d_ws, size_t ws_size,
                              hipStream_t stream) {
    const float* x = (const float*)d_in[0];
    const int N = in_sizes[0] / D;          // 10000
    float* out = (float*)d_out;

    // Workspace (floats): xT[64*XTP] | hxx[10048] | wsVal | wsIdx
    const size_t oXT = 0;
    const size_t oXX = (size_t)D * XTP;
    const size_t oV  = oXX + 10048;
    int nsplit = 13;
    while (nsplit > 1) {
        size_t need = (oV + 2 * (size_t)N * nsplit * K) * sizeof(float);
        if (need <= ws_size) break;
        nsplit = (nsplit == 13) ? 8 : (nsplit == 8) ? 4 : (nsplit == 4) ? 2 : 1;
    }
    float* xT    = (float*)d_ws + oXT;
    float* hxx   = (float*)d_ws + oXX;
    float* wsVal = (float*)d_ws + oV;
    int*   wsIdx = (int*)(wsVal + (size_t)N * nsplit * K);

    transpose_norms<<<XTP / 64, 256, 0, stream>>>(x, xT, hxx, N);

    const int rowBlocks = (N + 63) / 64;                 // 157
    dim3 grid(rowBlocks, nsplit);
    long long totalF4 = (long long)out_size / 4;
    int nBlocks = rowBlocks * nsplit;
    int f4PerBlock = (int)((totalF4 + nBlocks - 1) / nBlocks);
    topk_nolds<<<grid, 256, 0, stream>>>(xT, hxx, N, nsplit, wsVal, wsIdx,
                                         out, totalF4, f4PerBlock);

    merge_scatter<<<(N + 255) / 256, 256, 0, stream>>>(wsVal, wsIdx, out, N, nsplit);
}

// Round 5
// 588.241 us; speedup vs baseline: 1.9634x; 1.2739x over previous
//
#include <hip/hip_runtime.h>
#include <math.h>
#include <limits.h>

#define D 64
#define K 5
#define LK 8                  // per-lane / per-split candidate list length
#define GK 12                 // global candidates rescored per row
typedef unsigned long long u64;
typedef __bf16 bf16x8 __attribute__((ext_vector_type(8)));
typedef float  f32x4v __attribute__((ext_vector_type(4)));

// pack (value, idx) into sortable u64: bigger == (bigger value, then lower idx)
__device__ __forceinline__ u64 packKV(float v, int idx) {
    unsigned u = __float_as_uint(v);
    u = (u & 0x80000000u) ? ~u : (u | 0x80000000u);
    return ((u64)u << 32) | (unsigned)(~idx);
}

// value-then-lower-index tie-break insert (fp32 domain) — final rescore top-5
__device__ __forceinline__ void ins5tie(float v, int id, float bv[K], int bi[K]) {
    if ((v > bv[4]) || (v == bv[4] && id < bi[4])) {
        if ((v > bv[0]) || (v == bv[0] && id < bi[0]))      { bv[4]=bv[3];bi[4]=bi[3]; bv[3]=bv[2];bi[3]=bi[2]; bv[2]=bv[1];bi[2]=bi[1]; bv[1]=bv[0];bi[1]=bi[0]; bv[0]=v; bi[0]=id; }
        else if ((v > bv[1]) || (v == bv[1] && id < bi[1])) { bv[4]=bv[3];bi[4]=bi[3]; bv[3]=bv[2];bi[3]=bi[2]; bv[2]=bv[1];bi[2]=bi[1]; bv[1]=v; bi[1]=id; }
        else if ((v > bv[2]) || (v == bv[2] && id < bi[2])) { bv[4]=bv[3];bi[4]=bi[3]; bv[3]=bv[2];bi[3]=bi[2]; bv[2]=v; bi[2]=id; }
        else if ((v > bv[3]) || (v == bv[3] && id < bi[3])) { bv[4]=bv[3];bi[4]=bi[3]; bv[3]=v; bi[3]=id; }
        else                                                { bv[4]=v; bi[4]=id; }
    }
}

// branchless merge of two sorted-desc u64 lists, keep first LO into a[]
template<int LO, int LA, int LB>
__device__ __forceinline__ void mergeKeep(u64 a[LA], const u64 b[LB]) {
    u64 A[LA], B[LB], out[LO];
#pragma unroll
    for (int i = 0; i < LA; ++i) A[i] = a[i];
#pragma unroll
    for (int i = 0; i < LB; ++i) B[i] = b[i];
#pragma unroll
    for (int m = 0; m < LO; ++m) {
        bool ta = A[0] >= B[0];
        out[m] = ta ? A[0] : B[0];
#pragma unroll
        for (int i = 0; i < LA - 1; ++i) A[i] = ta ? A[i + 1] : A[i];
        A[LA - 1] = ta ? 0ull : A[LA - 1];
#pragma unroll
        for (int i = 0; i < LB - 1; ++i) B[i] = ta ? B[i] : B[i + 1];
        B[LB - 1] = ta ? B[LB - 1] : 0ull;
    }
#pragma unroll
    for (int m = 0; m < LO; ++m) a[m] = out[m];
}

// ---------------------------------------------------------------------------
// Prep: x[N][64] fp32 -> xb[N][64] bf16 (row-major) + xxf[i] = ||x_i||^2 fp32
// ---------------------------------------------------------------------------
__global__ __launch_bounds__(256) void prep(
    const float* __restrict__ x, __bf16* __restrict__ xb, float* __restrict__ xxf, int N)
{
    int i = blockIdx.x * 256 + threadIdx.x;
    if (i >= N) return;
    const float4* p = (const float4*)(x + (size_t)i * D);
    bf16x8* q = (bf16x8*)(xb + (size_t)i * D);
    float s = 0.f;
#pragma unroll
    for (int t = 0; t < 8; ++t) {
        float4 v0 = p[2 * t], v1 = p[2 * t + 1];
        s += v0.x * v0.x + v0.y * v0.y + v0.z * v0.z + v0.w * v0.w;
        s += v1.x * v1.x + v1.y * v1.y + v1.z * v1.z + v1.w * v1.w;
        bf16x8 o;
        o[0] = (__bf16)v0.x; o[1] = (__bf16)v0.y; o[2] = (__bf16)v0.z; o[3] = (__bf16)v0.w;
        o[4] = (__bf16)v1.x; o[5] = (__bf16)v1.y; o[6] = (__bf16)v1.z; o[7] = (__bf16)v1.w;
        q[t] = o;
    }
    xxf[i] = s;
}

// ---------------------------------------------------------------------------
// MFMA top-k filter. Block = 256 = 4 waves; wave w owns 16 rows
// (r0 = blockIdx.x*64 + w*16). Per col-tile (16 cols): A-frag = col points,
// B-frag = row points (held in regs), 2x mfma_f32_16x16x32_bf16 (k=64).
// C layout: col=lane&15 -> x-row fixed per lane; row=quad*4+reg -> col point.
// Per-lane top-8 (packed u64), butterfly-merged over the 4 lanes per row.
// Also zeroes a stripe of `out` per tile iter with NT stores.
// ---------------------------------------------------------------------------
__global__ __launch_bounds__(256) void topk_mfma(
    const __bf16* __restrict__ xb, const float* __restrict__ xxf, int N, int nsplit,
    u64* __restrict__ wsK, float* __restrict__ outZ, long long totalF4, int f4PerBlock)
{
    const int tid  = threadIdx.x;
    const int lane = tid & 63;
    const int wave = tid >> 6;
    const int l15  = lane & 15;
    const int q    = lane >> 4;            // col quad
    const int split = blockIdx.y;
    const int r0 = blockIdx.x * 64 + wave * 16;
    const int nTiles = (N + 15) / 16;      // 625

    // zero-fill bookkeeping
    const int bid = split * gridDim.x + blockIdx.x;
    long long zbeg = (long long)bid * f4PerBlock;
    long long zend = zbeg + f4PerBlock; if (zend > totalF4) zend = totalF4;
    const int nIters = (nTiles - split + nsplit - 1) / nsplit;
    const long long zChunk = (f4PerBlock + nIters - 1) / nIters;

    // B fragments: my row point, held across the whole loop
    int brow = r0 + l15; if (brow >= N) brow = 0;
    const bf16x8* bp = (const bf16x8*)(xb + (size_t)brow * D + q * 8);
    const bf16x8 B0 = bp[0];   // k = q*8 .. q*8+7
    const bf16x8 B1 = bp[4];   // k + 32

    u64 L[LK];
#pragma unroll
    for (int m = 0; m < LK; ++m) L[m] = 0ull;   // 0 < any real packed key

    int it = 0;
    for (int t = split; t < nTiles; t += nsplit, ++it) {
        // zero stripe (non-temporal; drains under the MFMA work)
        {
            long long s = zbeg + (long long)it * zChunk;
            long long e = s + zChunk; if (e > zend) e = zend;
            const f32x4v z = {0.f, 0.f, 0.f, 0.f};
            for (long long i = s + tid; i < e; i += 256)
                __builtin_nontemporal_store(z, (f32x4v*)(outZ + 4 * i));
        }

        const int c0 = t * 16;
        const bf16x8* ap = (const bf16x8*)(xb + (size_t)(c0 + l15) * D + q * 8);
        const bf16x8 A0 = ap[0];
        const bf16x8 A1 = ap[4];

        f32x4v acc = {0.f, 0.f, 0.f, 0.f};
        acc = __builtin_amdgcn_mfma_f32_16x16x32_bf16(A0, B0, acc, 0, 0, 0);
        acc = __builtin_amdgcn_mfma_f32_16x16x32_bf16(A1, B1, acc, 0, 0, 0);

        const f32x4v xc = *(const f32x4v*)(xxf + c0 + q * 4);
#pragma unroll
        for (int v = 0; v < 4; ++v) {
            float dk = fmaf(-0.5f, xc[v], acc[v]);    // key: ordering == distance ordering
            u64 key = packKV(dk, c0 + q * 4 + v);
            if (key > L[LK - 1]) {
                u64 carry = key;
#pragma unroll
                for (int m = 0; m < LK; ++m) {
                    u64 mx = (carry > L[m]) ? carry : L[m];
                    u64 mn = (carry > L[m]) ? L[m] : carry;
                    L[m] = mx; carry = mn;
                }
            }
        }
    }

    // butterfly merge across the 4 lanes sharing a row (xor 16, then 32)
#pragma unroll
    for (int mask = 16; mask <= 32; mask <<= 1) {
        u64 P[LK];
#pragma unroll
        for (int m = 0; m < LK; ++m) P[m] = __shfl_xor(L[m], mask);
        mergeKeep<LK, LK, LK>(L, P);
    }

    if (l15 == lane) {   // lanes 0..15 write
        int row = r0 + l15;
        if (row < N) {
            u64* dst = wsK + ((size_t)row * nsplit + split) * LK;
#pragma unroll
            for (int m = 0; m < LK; ++m) dst[m] = L[m];
        }
    }
}

// ---------------------------------------------------------------------------
// Per row: merge nsplit sorted-8 lists -> top-12 bf16 candidates, rescore in
// exact fp32, top-5 with reference tie-break, symmetric atomic scatter.
// ---------------------------------------------------------------------------
__global__ __launch_bounds__(256) void rescore_scatter(
    const u64* __restrict__ wsK, const float* __restrict__ x, const float* __restrict__ xxf,
    float* __restrict__ out, int N, int nsplit)
{
    int i = blockIdx.x * 256 + threadIdx.x;
    if (i >= N) return;

    const u64* lists = wsK + (size_t)i * nsplit * LK;
    u64 cur[GK];
#pragma unroll
    for (int m = 0; m < GK; ++m) cur[m] = (m < LK) ? lists[m] : 0ull;
    for (int s = 1; s < nsplit; ++s) {
        u64 b[LK];
#pragma unroll
        for (int m = 0; m < LK; ++m) b[m] = lists[s * LK + m];
        mergeKeep<GK, GK, LK>(cur, b);
    }

    // exact fp32 rescore of the GK candidates
    float xi[D];
    {
        const float4* p = (const float4*)(x + (size_t)i * D);
#pragma unroll
        for (int t = 0; t < 16; ++t) {
            float4 v = p[t];
            xi[4 * t] = v.x; xi[4 * t + 1] = v.y; xi[4 * t + 2] = v.z; xi[4 * t + 3] = v.w;
        }
    }
    const float nxi = xxf[i];

    float bv[K]; int bi[K];
#pragma unroll
    for (int m = 0; m < K; ++m) { bv[m] = -INFINITY; bi[m] = INT_MAX; }

#pragma unroll
    for (int m = 0; m < GK; ++m) {
        int j = (int)(~(unsigned)cur[m]);
        if ((unsigned)j >= (unsigned)N) continue;   // padding / invalid
        const float4* pj = (const float4*)(x + (size_t)j * D);
        float d0 = 0.f, d1 = 0.f, d2 = 0.f, d3 = 0.f;
#pragma unroll
        for (int t = 0; t < 16; ++t) {
            float4 v = pj[t];
            d0 = fmaf(xi[4 * t], v.x, d0);
            d1 = fmaf(xi[4 * t + 1], v.y, d1);
            d2 = fmaf(xi[4 * t + 2], v.z, d2);
            d3 = fmaf(xi[4 * t + 3], v.w, d3);
        }
        float val = 2.f * ((d0 + d1) + (d2 + d3)) - nxi - xxf[j];
        ins5tie(val, j, bv, bi);
    }

#pragma unroll
    for (int m = 0; m < K; ++m) {
        int j = bi[m]; float v = bv[m];
        if (j != i && (unsigned)j < (unsigned)N) {
            atomicAdd(out + (size_t)i * N + j, v);
            atomicAdd(out + (size_t)j * N + i, v);
        }
    }
}

// ---------------------------------------------------------------------------
extern "C" void kernel_launch(void* const* d_in, const int* in_sizes, int n_in,
                              void* d_out, int out_size, void* d_ws, size_t ws_size,
                              hipStream_t stream) {
    const float* x = (const float*)d_in[0];
    const int N = in_sizes[0] / D;          // 10000
    float* out = (float*)d_out;

    // Workspace: xb[N*64] bf16 | xxf[N] f32 | wsK[N*nsplit*8] u64
    const size_t oXB = 0;                               // bytes
    const size_t oXX = ((size_t)N * D * 2 + 255) & ~255ull;
    const size_t oWK = (oXX + (size_t)N * 4 + 255) & ~255ull;
    int nsplit = 8;
    while (nsplit > 1) {
        size_t need = oWK + (size_t)N * nsplit * LK * 8;
        if (need <= ws_size) break;
        nsplit >>= 1;
    }
    __bf16* xb  = (__bf16*)((char*)d_ws + oXB);
    float*  xxf = (float*)((char*)d_ws + oXX);
    u64*    wsK = (u64*)((char*)d_ws + oWK);

    prep<<<(N + 255) / 256, 256, 0, stream>>>(x, xb, xxf, N);

    const int rowBlocks = (N + 63) / 64;                 // 157
    dim3 grid(rowBlocks, nsplit);
    long long totalF4 = (long long)out_size / 4;         // 25e6
    int nBlocks = rowBlocks * nsplit;
    int f4PerBlock = (int)((totalF4 + nBlocks - 1) / nBlocks);
    topk_mfma<<<grid, 256, 0, stream>>>(xb, xxf, N, nsplit, wsK,
                                        out, totalF4, f4PerBlock);

    rescore_scatter<<<(N + 255) / 256, 256, 0, stream>>>(wsK, x, xxf, out, N, nsplit);
}

// Round 6
// 546.836 us; speedup vs baseline: 2.1120x; 1.0757x over previous
//
#include <hip/hip_runtime.h>
#include <math.h>
#include <limits.h>

#define D 64
#define K 5
#define LK 8                  // per-lane / per-split candidate list length
#define GK 12                 // global candidates rescored per row
#define NSPLIT 8
typedef unsigned long long u64;
typedef __bf16 bf16x8 __attribute__((ext_vector_type(8)));
typedef float  f32x4v __attribute__((ext_vector_type(4)));

// monotone map: bigger key == (bigger value, then lower idx)
__device__ __forceinline__ u64 packKV(float v, int idx) {
    unsigned u = __float_as_uint(v);
    u ^= ((unsigned)((int)u >> 31)) | 0x80000000u;
    return ((u64)u << 32) | (unsigned)(~idx);
}
__device__ __forceinline__ float unpackV(u64 key) {
    unsigned hu = (unsigned)(key >> 32);
    return (hu & 0x80000000u) ? __uint_as_float(hu & 0x7fffffffu)
                              : __uint_as_float(~hu);
}

// branchless merge of two sorted-desc u64 lists, keep first LO into a[]
template<int LO, int LA, int LB>
__device__ __forceinline__ void mergeKeep(u64 a[LA], const u64 b[LB]) {
    u64 A[LA], B[LB], out[LO];
#pragma unroll
    for (int i = 0; i < LA; ++i) A[i] = a[i];
#pragma unroll
    for (int i = 0; i < LB; ++i) B[i] = b[i];
#pragma unroll
    for (int m = 0; m < LO; ++m) {
        bool ta = A[0] >= B[0];
        out[m] = ta ? A[0] : B[0];
#pragma unroll
        for (int i = 0; i < LA - 1; ++i) A[i] = ta ? A[i + 1] : A[i];
        A[LA - 1] = ta ? 0ull : A[LA - 1];
#pragma unroll
        for (int i = 0; i < LB - 1; ++i) B[i] = ta ? B[i] : B[i + 1];
        B[LB - 1] = ta ? B[LB - 1] : 0ull;
    }
#pragma unroll
    for (int m = 0; m < LO; ++m) a[m] = out[m];
}

// ---------------------------------------------------------------------------
// Prep: x[N][64] fp32 -> xb[N][64] bf16 + xxf[i] = ||x_i||^2 fp32
// ---------------------------------------------------------------------------
__global__ __launch_bounds__(256) void prep(
    const float* __restrict__ x, __bf16* __restrict__ xb, float* __restrict__ xxf, int N)
{
    int i = blockIdx.x * 256 + threadIdx.x;
    if (i >= N) return;
    const float4* p = (const float4*)(x + (size_t)i * D);
    bf16x8* q = (bf16x8*)(xb + (size_t)i * D);
    float s = 0.f;
#pragma unroll
    for (int t = 0; t < 8; ++t) {
        float4 v0 = p[2 * t], v1 = p[2 * t + 1];
        s += v0.x * v0.x + v0.y * v0.y + v0.z * v0.z + v0.w * v0.w;
        s += v1.x * v1.x + v1.y * v1.y + v1.z * v1.z + v1.w * v1.w;
        bf16x8 o;
        o[0] = (__bf16)v0.x; o[1] = (__bf16)v0.y; o[2] = (__bf16)v0.z; o[3] = (__bf16)v0.w;
        o[4] = (__bf16)v1.x; o[5] = (__bf16)v1.y; o[6] = (__bf16)v1.z; o[7] = (__bf16)v1.w;
        q[t] = o;
    }
    xxf[i] = s;
}

// ---------------------------------------------------------------------------
// MFMA top-k filter. Wave w owns 16 rows (B-frag = row points, held in regs).
// Per 16-col tile: A-frag = col points, 2x mfma_f32_16x16x32_bf16 (k=64).
// C layout: x-row fixed per lane (col=lane&15), 4 col-points (quad*4+reg).
// Per-lane sorted top-8 (packed u64); butterfly over the 4 quads at the end.
// All loop-varying addresses are pointer-bumped. Zeroes a stripe of `out`
// per tile iteration with NT stores (drains under the compute).
// ---------------------------------------------------------------------------
__global__ __launch_bounds__(256) void topk_mfma(
    const __bf16* __restrict__ xb, const float* __restrict__ xxf, int N,
    u64* __restrict__ wsK, float* __restrict__ outZ, long long totalF4, int f4PerBlock)
{
    const int tid  = threadIdx.x;
    const int lane = tid & 63;
    const int wave = tid >> 6;
    const int l15  = lane & 15;
    const int q    = lane >> 4;            // col quad
    const int split = blockIdx.y;
    const int r0 = blockIdx.x * 64 + wave * 16;
    const int nTiles = (N + 15) / 16;      // 625

    // zero-fill bookkeeping (incremental)
    const int bid = split * gridDim.x + blockIdx.x;
    long long zcur = (long long)bid * f4PerBlock;
    long long zend = zcur + f4PerBlock; if (zend > totalF4) zend = totalF4;
    const int nIters = (nTiles - split + NSPLIT - 1) / NSPLIT;
    const long long zChunk = (f4PerBlock + nIters - 1) / nIters;

    // B fragments: my row point, held across the whole loop
    int brow = r0 + l15; if (brow >= N) brow = 0;
    const bf16x8* bp = (const bf16x8*)(xb + (size_t)brow * D) + q;
    const bf16x8 B0 = bp[0];   // k = q*8 .. q*8+7
    const bf16x8 B1 = bp[4];   // k + 32

    // pointer-bumped loop state
    const bf16x8* ap = (const bf16x8*)xb + (size_t)(split * 16 + l15) * (D / 8) + q;
    const float* xcp = xxf + split * 16 + q * 4;
    int cbase = split * 16 + q * 4;
    const int apBump = NSPLIT * 16 * (D / 8);
    const int xcBump = NSPLIT * 16;

    u64 L[LK];
#pragma unroll
    for (int m = 0; m < LK; ++m) L[m] = 0ull;   // 0 < any real packed key

    for (int t = split; t < nTiles; t += NSPLIT) {
        // zero stripe (non-temporal)
        {
            long long e = zcur + zChunk; if (e > zend) e = zend;
            const f32x4v z = {0.f, 0.f, 0.f, 0.f};
            for (long long i = zcur + tid; i < e; i += 256)
                __builtin_nontemporal_store(z, (f32x4v*)(outZ + 4 * i));
            zcur += zChunk;
        }

        const bf16x8 A0 = ap[0];
        const bf16x8 A1 = ap[4];
        ap += apBump;

        f32x4v acc = {0.f, 0.f, 0.f, 0.f};
        acc = __builtin_amdgcn_mfma_f32_16x16x32_bf16(A0, B0, acc, 0, 0, 0);
        acc = __builtin_amdgcn_mfma_f32_16x16x32_bf16(A1, B1, acc, 0, 0, 0);

        const f32x4v xc = *(const f32x4v*)xcp;
        xcp += xcBump;

#pragma unroll
        for (int v = 0; v < 4; ++v) {
            float dk = fmaf(-0.5f, xc[v], acc[v]);    // ordering == distance ordering
            u64 key = packKV(dk, cbase + v);
            if (key > L[LK - 1]) {
                u64 carry = key;
#pragma unroll
                for (int m = 0; m < LK; ++m) {
                    u64 mx = (carry > L[m]) ? carry : L[m];
                    u64 mn = (carry > L[m]) ? L[m] : carry;
                    L[m] = mx; carry = mn;
                }
            }
        }
        cbase += xcBump;
    }

    // butterfly merge across the 4 quads sharing a row
#pragma unroll
    for (int mask = 16; mask <= 32; mask <<= 1) {
        u64 P[LK];
#pragma unroll
        for (int m = 0; m < LK; ++m) P[m] = __shfl_xor(L[m], mask);
        mergeKeep<LK, LK, LK>(L, P);
    }

    if (lane < 16) {
        int row = r0 + l15;
        if (row < N) {
            u64* dst = wsK + ((size_t)row * NSPLIT + split) * LK;
#pragma unroll
            for (int m = 0; m < LK; ++m) dst[m] = L[m];
        }
    }
}

// ---------------------------------------------------------------------------
// 4 lanes per row. Each lane merges 2 split-lists; 2 shfl_xor butterflies
// give the exact bf16-top-12 (tree keep-12 == global top-12). Each lane
// rescores 3 candidates in exact fp32; final top-5 via packed-u64 butterfly
// (ordering == value-desc, index-asc == reference tie-break). Lane 0 of each
// row does the symmetric atomic scatter. No big per-thread arrays -> no spill.
// ---------------------------------------------------------------------------
__global__ __launch_bounds__(256) void rescore_scatter(
    const u64* __restrict__ wsK, const float* __restrict__ x, const float* __restrict__ xxf,
    float* __restrict__ out, int N)
{
    const int tid  = threadIdx.x;
    const int lane = tid & 63;
    const int wave = tid >> 6;
    const int sub  = lane & 3;
    const int row  = blockIdx.x * 64 + wave * 16 + (lane >> 2);
    const bool vrow = (row < N);
    const int rr = vrow ? row : 0;

    // merge my 2 lists, then butterfly to global top-12
    u64 cur[GK];
    {
        const u64* Lp = wsK + ((size_t)rr * NSPLIT + 2 * sub) * LK;
        u64 b[LK];
#pragma unroll
        for (int m = 0; m < LK; ++m) { cur[m] = Lp[m]; b[m] = Lp[LK + m]; }
#pragma unroll
        for (int m = LK; m < GK; ++m) cur[m] = 0ull;
        mergeKeep<GK, GK, LK>(cur, b);
    }
#pragma unroll
    for (int mask = 1; mask <= 2; mask <<= 1) {
        u64 P[GK];
#pragma unroll
        for (int m = 0; m < GK; ++m) P[m] = __shfl_xor(cur[m], mask);
        mergeKeep<GK, GK, GK>(cur, P);
    }

    // exact fp32 rescore of my 3 candidates
    const float nxi = xxf[rr];
    int   cj[3]; bool cval[3];
    float d[3] = {0.f, 0.f, 0.f};
    const f32x4v* pj[3];
#pragma unroll
    for (int c = 0; c < 3; ++c) {
        int j = (int)(~(unsigned)cur[sub * 3 + c]);
        cval[c] = ((unsigned)j < (unsigned)N);
        cj[c] = cval[c] ? j : 0;
        pj[c] = (const f32x4v*)(x + (size_t)cj[c] * D);
    }
    const f32x4v* xip = (const f32x4v*)(x + (size_t)rr * D);
#pragma unroll
    for (int t = 0; t < 16; ++t) {
        const f32x4v xv = xip[t];
#pragma unroll
        for (int c = 0; c < 3; ++c) {
            const f32x4v pv = pj[c][t];
            d[c] = fmaf(xv[0], pv[0], d[c]);
            d[c] = fmaf(xv[1], pv[1], d[c]);
            d[c] = fmaf(xv[2], pv[2], d[c]);
            d[c] = fmaf(xv[3], pv[3], d[c]);
        }
    }
    u64 F[K];
#pragma unroll
    for (int c = 0; c < 3; ++c) {
        float val = 2.f * d[c] - nxi - xxf[cj[c]];
        F[c] = cval[c] ? packKV(val, cj[c]) : 0ull;
    }
    F[3] = 0ull; F[4] = 0ull;
    // sort first 3 desc
    { u64 a0=F[0],a1=F[1],a2=F[2];
      if (a0 < a1) { u64 t0=a0; a0=a1; a1=t0; }
      if (a1 < a2) { u64 t0=a1; a1=a2; a2=t0; }
      if (a0 < a1) { u64 t0=a0; a0=a1; a1=t0; }
      F[0]=a0; F[1]=a1; F[2]=a2; }
#pragma unroll
    for (int mask = 1; mask <= 2; mask <<= 1) {
        u64 P[K];
#pragma unroll
        for (int m = 0; m < K; ++m) P[m] = __shfl_xor(F[m], mask);
        mergeKeep<K, K, K>(F, P);
    }

    if (sub == 0 && vrow) {
#pragma unroll
        for (int m = 0; m < K; ++m) {
            int j = (int)(~(unsigned)F[m]);
            if ((unsigned)j < (unsigned)N && j != row) {
                float v = unpackV(F[m]);
                atomicAdd(out + (size_t)row * N + j, v);
                atomicAdd(out + (size_t)j * N + row, v);
            }
        }
    }
}

// ---------------------------------------------------------------------------
extern "C" void kernel_launch(void* const* d_in, const int* in_sizes, int n_in,
                              void* d_out, int out_size, void* d_ws, size_t ws_size,
                              hipStream_t stream) {
    const float* x = (const float*)d_in[0];
    const int N = in_sizes[0] / D;          // 10000
    float* out = (float*)d_out;

    // Workspace: xb[N*64] bf16 | xxf[N] f32 | wsK[N*NSPLIT*LK] u64  (~6.5 MB;
    // ws_size ≈ 1.6 GB per the harness fill counters)
    const size_t oXB = 0;
    const size_t oXX = ((size_t)N * D * 2 + 255) & ~255ull;
    const size_t oWK = (oXX + (size_t)N * 4 + 255) & ~255ull;
    __bf16* xb  = (__bf16*)((char*)d_ws + oXB);
    float*  xxf = (float*)((char*)d_ws + oXX);
    u64*    wsK = (u64*)((char*)d_ws + oWK);

    prep<<<(N + 255) / 256, 256, 0, stream>>>(x, xb, xxf, N);

    const int rowBlocks = (N + 63) / 64;                 // 157
    dim3 grid(rowBlocks, NSPLIT);                        // 1256 blocks
    long long totalF4 = (long long)out_size / 4;         // 25e6
    int nBlocks = rowBlocks * NSPLIT;
    int f4PerBlock = (int)((totalF4 + nBlocks - 1) / nBlocks);
    topk_mfma<<<grid, 256, 0, stream>>>(xb, xxf, N, wsK, out, totalF4, f4PerBlock);

    rescore_scatter<<<rowBlocks, 256, 0, stream>>>(wsK, x, xxf, out, N);
}